// Round 1
// baseline (417.152 us; speedup 1.0000x reference)
//
#include <hip/hip_runtime.h>

typedef __attribute__((ext_vector_type(8))) short short8;
typedef __attribute__((ext_vector_type(4))) float f32x4;

#define M_TOTAL 40770   // number of spans
#define NTOK    2048
#define HD      512
#define BM      64      // spans per block in main kernel

__device__ __forceinline__ short f2bf(float f) {
  unsigned u = __builtin_bit_cast(unsigned, f);
  u += 0x7FFFu + ((u >> 16) & 1u);
  return (short)(u >> 16);
}

// ---------------------------------------------------------------------------
// K1: embW[t] = concat(We_pos[tag], We_wrd[word]) @ dan_w0   [2048,512] fp32
// block: 8 tokens, 512 threads (thread owns one output column n)
// ---------------------------------------------------------------------------
__global__ void k_embW(const int* __restrict__ sentence, const int* __restrict__ pos_tags,
                       const float* __restrict__ We_wrd, const float* __restrict__ We_pos,
                       const float* __restrict__ dan_w0, float* __restrict__ embW) {
  __shared__ float rowf[8][512];   // 16 KB
  const int tid = threadIdx.x;
  const int b = blockIdx.x;
  for (int p = 0; p < 8; ++p) {
    int idx = p * 512 + tid;
    int m = idx >> 9, k = idx & 511;
    int tk = b * 8 + m;
    rowf[m][k] = (k < 256) ? We_pos[pos_tags[tk] * 256 + k]
                           : We_wrd[sentence[tk] * 256 + (k - 256)];
  }
  __syncthreads();
  float acc[8] = {0.f, 0.f, 0.f, 0.f, 0.f, 0.f, 0.f, 0.f};
  const int n = tid;
  for (int k4 = 0; k4 < 512; k4 += 4) {
    float w0 = dan_w0[(k4 + 0) * 512 + n];
    float w1 = dan_w0[(k4 + 1) * 512 + n];
    float w2 = dan_w0[(k4 + 2) * 512 + n];
    float w3 = dan_w0[(k4 + 3) * 512 + n];
#pragma unroll
    for (int m = 0; m < 8; ++m) {
      float4 rv = *(const float4*)&rowf[m][k4];
      acc[m] += rv.x * w0;
      acc[m] += rv.y * w1;
      acc[m] += rv.z * w2;
      acc[m] += rv.w * w3;
    }
  }
#pragma unroll
  for (int m = 0; m < 8; ++m)
    embW[(size_t)(b * 8 + m) * 512 + n] = acc[m];
}

// ---------------------------------------------------------------------------
// K2a/b/c: column-wise inclusive scan of embW with leading zero row -> csumW
// ---------------------------------------------------------------------------
__global__ void k_scan_a(const float* __restrict__ embW, float* __restrict__ cSum) {
  int b = blockIdx.x, t = threadIdx.x;
  int ch = b >> 1, cc = (b & 1) * 256 + t;
  float s = 0.f;
  for (int r = 0; r < 128; ++r) s += embW[(size_t)(ch * 128 + r) * 512 + cc];
  cSum[ch * 512 + cc] = s;
}
__global__ void k_scan_b(const float* __restrict__ cSum, float* __restrict__ cPre) {
  int cc = blockIdx.x * 256 + threadIdx.x;
  float run = 0.f;
  for (int ch = 0; ch < 16; ++ch) {
    cPre[ch * 512 + cc] = run;
    run += cSum[ch * 512 + cc];
  }
}
__global__ void k_scan_c(const float* __restrict__ embW, const float* __restrict__ cPre,
                         float* __restrict__ csumW) {
  int b = blockIdx.x, t = threadIdx.x;
  int ch = b >> 1, cc = (b & 1) * 256 + t;
  float run = cPre[ch * 512 + cc];
  if (ch == 0) csumW[cc] = 0.f;
  for (int r = 0; r < 128; ++r) {
    run += embW[(size_t)(ch * 128 + r) * 512 + cc];
    csumW[(size_t)(ch * 128 + r + 1) * 512 + cc] = run;
  }
}

// ---------------------------------------------------------------------------
// K3: pre-shuffle dan_w1 and ws_w0[0:512] into MFMA B-fragment-linear bf16:
//     shuf[((nt*16+kt)*64+lane)*8 + j] = W[kt*32 + 8*(lane>>4)+j][nt*16+(lane&15)]
// ---------------------------------------------------------------------------
__global__ void k_prepack(const float* __restrict__ dan_w1, const float* __restrict__ ws_w0,
                          short* __restrict__ w1_shuf, short* __restrict__ w0s_shuf) {
  int o = blockIdx.x * 256 + threadIdx.x;  // 262144 total
  int j = o & 7, l = (o >> 3) & 63, kt = (o >> 9) & 15, nt = o >> 13;
  int k = kt * 32 + 8 * (l >> 4) + j;
  int n = nt * 16 + (l & 15);
  w1_shuf[o] = f2bf(dan_w1[(size_t)k * 512 + n]);
  w0s_shuf[o] = f2bf(ws_w0[(size_t)k * 512 + n]);
}

// ---------------------------------------------------------------------------
// K4: positional-feature tables: T*[v][n] = sum_d pe(v)[d] * ws_w0[512+32*tbl+d][n]
// block = 8 consecutive values of one table; d-outer / v-inner register reuse.
// ---------------------------------------------------------------------------
__global__ void k_tables(const float* __restrict__ ws_w0, float* __restrict__ Ts,
                         float* __restrict__ Te, float* __restrict__ Tl,
                         float* __restrict__ Tm) {
  __shared__ float pe8[8][32];  // 1 KB
  const int b = blockIdx.x, t = threadIdx.x;
  int tbl, v0, tsize;
  float* outp;
  if (b < 256)      { tbl = 0; v0 = b * 8;         tsize = 2048; outp = Ts; }
  else if (b < 513) { tbl = 1; v0 = (b - 256) * 8; tsize = 2049; outp = Te; }
  else if (b < 516) { tbl = 2; v0 = (b - 513) * 8; tsize = 21;   outp = Tl; }
  else              { tbl = 3; v0 = (b - 516) * 8; tsize = 4096; outp = Tm; }
  if (t < 128) {
    int v = t >> 4, d = t & 15;
    float x = (float)(v0 + v);
    if (tbl == 3) x *= 0.5f;  // Tm indexed by (start+end); mid = 0.5*(start+end)
    float freq = expf(-0.5756462732485115f * (float)d);  // ln(1e4)/16
    float ang = x * freq;
    pe8[v][d] = sinf(ang);
    pe8[v][d + 16] = cosf(ang);
  }
  __syncthreads();
  float a0[8] = {0.f, 0.f, 0.f, 0.f, 0.f, 0.f, 0.f, 0.f};
  float a1[8] = {0.f, 0.f, 0.f, 0.f, 0.f, 0.f, 0.f, 0.f};
  for (int d = 0; d < 32; ++d) {
    float wv0 = ws_w0[(size_t)(512 + 32 * tbl + d) * 512 + t];
    float wv1 = ws_w0[(size_t)(512 + 32 * tbl + d) * 512 + t + 256];
#pragma unroll
    for (int v = 0; v < 8; ++v) {
      float p = pe8[v][d];
      a0[v] += p * wv0;
      a1[v] += p * wv1;
    }
  }
#pragma unroll
  for (int v = 0; v < 8; ++v) {
    int val = v0 + v;
    if (val < tsize) {
      outp[(size_t)val * 512 + t] = a0[v];
      outp[(size_t)val * 512 + t + 256] = a1[v];
    }
  }
}

// ---------------------------------------------------------------------------
// K5: main fused kernel. 64 spans/block, 256 threads (4 waves, wave w owns
// output cols [128w,128w+128)). h -> LDS(bf16,XOR-swz) -> MFMA -> phrase ->
// same LDS -> MFMA -> epilogue (table gathers + relu + dot ws_w1).
// LDS = exactly 64 KiB -> 2 blocks/CU.
// ---------------------------------------------------------------------------
__launch_bounds__(256, 2)
__global__ void k_main(const int* __restrict__ spans_start, const int* __restrict__ spans_len,
                       const float* __restrict__ csumW, const short* __restrict__ w1_shuf,
                       const short* __restrict__ w0s_shuf, const float* __restrict__ Ts,
                       const float* __restrict__ Te, const float* __restrict__ Tl,
                       const float* __restrict__ Tm, const float* __restrict__ b0,
                       const float* __restrict__ b1, const float* __restrict__ bs0,
                       const float* __restrict__ ws_w1, const float* __restrict__ ws_b1,
                       float* __restrict__ out) {
  __shared__ short tileS[BM * 512];  // 64 KiB: holds h, then phrase, then scores

  const int tid = threadIdx.x;
  const int lane = tid & 63;
  const int w = tid >> 6;        // wave 0..3
  const int g = lane >> 4;       // 16-lane group 0..3
  const int c = lane & 15;
  const int cb = blockIdx.x * BM;

  // ---- Phase 1: h[m][k] = relu((csumW[en]-csumW[st])*inv + b0[k]) -> tileS
  const float4 bb0 = *(const float4*)(b0 + 8 * lane);
  const float4 bb1 = *(const float4*)(b0 + 8 * lane + 4);
  for (int rep = 0; rep < 16; ++rep) {
    int m = 4 * rep + w;  // wave-uniform row
    int ch = cb + m;
    if (ch >= M_TOTAL) ch = M_TOTAL - 1;
    int st = spans_start[ch];
    int ln = spans_len[ch];
    int en = st + ln;
    float inv = 1.0f / (float)ln;
    const float* pe_ = csumW + (size_t)en * 512 + 8 * lane;
    const float* ps_ = csumW + (size_t)st * 512 + 8 * lane;
    float4 e0 = *(const float4*)pe_, e1 = *(const float4*)(pe_ + 4);
    float4 s0 = *(const float4*)ps_, s1 = *(const float4*)(ps_ + 4);
    float hv[8];
    hv[0] = (e0.x - s0.x) * inv + bb0.x;
    hv[1] = (e0.y - s0.y) * inv + bb0.y;
    hv[2] = (e0.z - s0.z) * inv + bb0.z;
    hv[3] = (e0.w - s0.w) * inv + bb0.w;
    hv[4] = (e1.x - s1.x) * inv + bb1.x;
    hv[5] = (e1.y - s1.y) * inv + bb1.y;
    hv[6] = (e1.z - s1.z) * inv + bb1.z;
    hv[7] = (e1.w - s1.w) * inv + bb1.w;
    short8 hs;
#pragma unroll
    for (int j = 0; j < 8; ++j) hs[j] = f2bf(fmaxf(hv[j], 0.f));
    int idx = m * 512 + (((16 * lane) ^ ((m & 7) << 4)) >> 1);
    *(short8*)(tileS + idx) = hs;
  }
  __syncthreads();

  const f32x4 zero4 = {0.f, 0.f, 0.f, 0.f};
  f32x4 acc[4][8];

  // GEMM over tileS (A, bf16, XOR-swizzled) x shuffled weights (B). K=512.
  auto do_gemm = [&](const short* __restrict__ Wsh) {
#pragma unroll
    for (int mt = 0; mt < 4; ++mt)
#pragma unroll
      for (int i = 0; i < 8; ++i) acc[mt][i] = zero4;
    const short8* W = (const short8*)Wsh;
#pragma unroll 2
    for (int kt = 0; kt < 16; ++kt) {
      short8 a[4];
#pragma unroll
      for (int mt = 0; mt < 4; ++mt) {
        int row = c + 16 * mt;
        int idx = row * 512 + (((kt * 64 + 16 * g) ^ ((c & 7) << 4)) >> 1);
        a[mt] = *(const short8*)(tileS + idx);
      }
#pragma unroll
      for (int i = 0; i < 8; ++i) {
        short8 bfrag = W[((8 * w + i) * 16 + kt) * 64 + lane];
#pragma unroll
        for (int mt = 0; mt < 4; ++mt)
          acc[mt][i] = __builtin_amdgcn_mfma_f32_16x16x32_bf16(a[mt], bfrag, acc[mt][i], 0, 0, 0);
      }
    }
  };

  // ---- Phase 2: phrase = relu(h @ w1 + b1)
  do_gemm(w1_shuf);
  __syncthreads();  // all reads of h complete before overwriting tileS
#pragma unroll
  for (int i = 0; i < 8; ++i) {
    int n = c + 16 * (8 * w + i);
    float bias = b1[n];
#pragma unroll
    for (int mt = 0; mt < 4; ++mt) {
#pragma unroll
      for (int r = 0; r < 4; ++r) {
        int m = 16 * mt + 4 * g + r;
        float v = acc[mt][i][r] + bias;
        v = v > 0.f ? v : 0.f;
        int idx = m * 512 + ((((2 * n) ^ ((m & 7) << 4))) >> 1);
        tileS[idx] = f2bf(v);
      }
    }
  }
  __syncthreads();

  // ---- Phase 3: s_pre = phrase @ ws_w0[0:512]
  do_gemm(w0s_shuf);
  __syncthreads();  // phrase reads done; tileS reusable for score partials

  // ---- Phase 4: s = relu(s_pre + bs0 + Ts+Te+Tl+Tm); score = s . ws_w1
  float* scoreF = (float*)tileS;
  float bsv[8], w1v[8];
#pragma unroll
  for (int i = 0; i < 8; ++i) {
    int n = c + 16 * (8 * w + i);
    bsv[i] = bs0[n];
    w1v[i] = ws_w1[n];
  }
#pragma unroll
  for (int mt = 0; mt < 4; ++mt) {
#pragma unroll
    for (int r = 0; r < 4; ++r) {
      int m = 16 * mt + 4 * g + r;
      int ch = cb + m;
      if (ch >= M_TOTAL) ch = M_TOTAL - 1;
      int st = spans_start[ch];
      int ln = spans_len[ch];
      int en = st + ln;
      const float* ts = Ts + (size_t)st * 512;
      const float* te = Te + (size_t)en * 512;
      const float* tl = Tl + (size_t)ln * 512;
      const float* tm = Tm + (size_t)(st + en) * 512;
      float p = 0.f;
#pragma unroll
      for (int i = 0; i < 8; ++i) {
        int n = c + 16 * (8 * w + i);
        float v = acc[mt][i][r] + bsv[i] + ts[n] + te[n] + tl[n] + tm[n];
        p += fmaxf(v, 0.f) * w1v[i];
      }
      p += __shfl_xor(p, 1);
      p += __shfl_xor(p, 2);
      p += __shfl_xor(p, 4);
      p += __shfl_xor(p, 8);
      if (c == 0) scoreF[w * 64 + m] = p;
    }
  }
  __syncthreads();
  if (tid < 64) {
    int ch = cb + tid;
    if (ch < M_TOTAL)
      out[ch] = scoreF[tid] + scoreF[64 + tid] + scoreF[128 + tid] + scoreF[192 + tid] + ws_b1[0];
  }
}

// ---------------------------------------------------------------------------
extern "C" void kernel_launch(void* const* d_in, const int* in_sizes, int n_in,
                              void* d_out, int out_size, void* d_ws, size_t ws_size,
                              hipStream_t stream) {
  const int* sentence = (const int*)d_in[0];
  const int* pos_tags = (const int*)d_in[1];
  const int* sp_start = (const int*)d_in[2];
  const int* sp_len   = (const int*)d_in[3];
  const float* We_wrd = (const float*)d_in[4];
  const float* We_pos = (const float*)d_in[5];
  const float* dan_w0 = (const float*)d_in[6];
  const float* dan_b0 = (const float*)d_in[7];
  const float* dan_w1 = (const float*)d_in[8];
  const float* dan_b1 = (const float*)d_in[9];
  const float* ws_w0  = (const float*)d_in[10];
  const float* ws_b0  = (const float*)d_in[11];
  const float* ws_w1  = (const float*)d_in[12];
  const float* ws_b1  = (const float*)d_in[13];
  float* out = (float*)d_out;

  char* ws = (char*)d_ws;
  float* embW    = (float*)(ws);              // 4,194,304 B
  float* csumW   = (float*)(ws + 4194304);    // 4,196,352 B
  float* cSum    = (float*)(ws + 8390656);    //    32,768 B
  float* cPre    = (float*)(ws + 8423424);    //    32,768 B
  short* w1_shuf = (short*)(ws + 8456192);    //   524,288 B
  short* w0s_shuf= (short*)(ws + 8980480);    //   524,288 B
  float* Ts      = (float*)(ws + 9504768);    // 4,194,304 B
  float* Te      = (float*)(ws + 13699072);   // 4,196,352 B
  float* Tl      = (float*)(ws + 17895424);   //    43,008 B
  float* Tm      = (float*)(ws + 17938432);   // 8,388,608 B -> total 26,327,040 B

  k_embW<<<256, 512, 0, stream>>>(sentence, pos_tags, We_wrd, We_pos, dan_w0, embW);
  k_scan_a<<<32, 256, 0, stream>>>(embW, cSum);
  k_scan_b<<<2, 256, 0, stream>>>(cSum, cPre);
  k_scan_c<<<32, 256, 0, stream>>>(embW, cPre, csumW);
  k_prepack<<<1024, 256, 0, stream>>>(dan_w1, ws_w0, w1_shuf, w0s_shuf);
  k_tables<<<1028, 256, 0, stream>>>(ws_w0, Ts, Te, Tl, Tm);
  k_main<<<638, 256, 0, stream>>>(sp_start, sp_len, csumW, w1_shuf, w0s_shuf,
                                  Ts, Te, Tl, Tm, dan_b0, dan_b1, ws_b0, ws_w1, ws_b1, out);
}

// Round 4
// 278.843 us; speedup vs baseline: 1.4960x; 1.4960x over previous
//
#include <hip/hip_runtime.h>

typedef __attribute__((ext_vector_type(8))) short short8;
typedef __attribute__((ext_vector_type(4))) float f32x4;

#define M_TOTAL 40770   // number of spans
#define NTOK    2048
#define HD      512
#define BM      64      // spans per block in main kernel

__device__ __forceinline__ short f2bf(float f) {
  unsigned u = __builtin_bit_cast(unsigned, f);
  u += 0x7FFFu + ((u >> 16) & 1u);
  return (short)(u >> 16);
}

// ---------------------------------------------------------------------------
// K1: embW[t] = concat(We_pos[tag], We_wrd[word]) @ dan_w0   [2048,512] fp32
// block: 16 tokens, 512 threads (thread owns one output column n)
// ---------------------------------------------------------------------------
__global__ void k_embW(const int* __restrict__ sentence, const int* __restrict__ pos_tags,
                       const float* __restrict__ We_wrd, const float* __restrict__ We_pos,
                       const float* __restrict__ dan_w0, float* __restrict__ embW) {
  __shared__ float rowf[16][512];   // 32 KB
  const int tid = threadIdx.x;
  const int b = blockIdx.x;
  for (int p = 0; p < 16; ++p) {
    int idx = p * 512 + tid;
    int m = idx >> 9, k = idx & 511;
    int tk = b * 16 + m;
    rowf[m][k] = (k < 256) ? We_pos[pos_tags[tk] * 256 + k]
                           : We_wrd[sentence[tk] * 256 + (k - 256)];
  }
  __syncthreads();
  float acc[16];
#pragma unroll
  for (int m = 0; m < 16; ++m) acc[m] = 0.f;
  const int n = tid;
  for (int k4 = 0; k4 < 512; k4 += 4) {
    float w0 = dan_w0[(k4 + 0) * 512 + n];
    float w1 = dan_w0[(k4 + 1) * 512 + n];
    float w2 = dan_w0[(k4 + 2) * 512 + n];
    float w3 = dan_w0[(k4 + 3) * 512 + n];
#pragma unroll
    for (int m = 0; m < 16; ++m) {
      float4 rv = *(const float4*)&rowf[m][k4];
      acc[m] += rv.x * w0;
      acc[m] += rv.y * w1;
      acc[m] += rv.z * w2;
      acc[m] += rv.w * w3;
    }
  }
#pragma unroll
  for (int m = 0; m < 16; ++m)
    embW[(size_t)(b * 16 + m) * 512 + n] = acc[m];
}

// ---------------------------------------------------------------------------
// K2a/b/c: column-wise inclusive scan of embW with leading zero row -> csumW
// ---------------------------------------------------------------------------
__global__ void k_scan_a(const float* __restrict__ embW, float* __restrict__ cSum) {
  int b = blockIdx.x, t = threadIdx.x;
  int ch = b >> 1, cc = (b & 1) * 256 + t;
  float s = 0.f;
  for (int r = 0; r < 128; ++r) s += embW[(size_t)(ch * 128 + r) * 512 + cc];
  cSum[ch * 512 + cc] = s;
}
__global__ void k_scan_b(const float* __restrict__ cSum, float* __restrict__ cPre) {
  int cc = blockIdx.x * 256 + threadIdx.x;
  float run = 0.f;
  for (int ch = 0; ch < 16; ++ch) {
    cPre[ch * 512 + cc] = run;
    run += cSum[ch * 512 + cc];
  }
}
__global__ void k_scan_c(const float* __restrict__ embW, const float* __restrict__ cPre,
                         float* __restrict__ csumW) {
  int b = blockIdx.x, t = threadIdx.x;
  int ch = b >> 1, cc = (b & 1) * 256 + t;
  float run = cPre[ch * 512 + cc];
  if (ch == 0) csumW[cc] = 0.f;
  for (int r = 0; r < 128; ++r) {
    run += embW[(size_t)(ch * 128 + r) * 512 + cc];
    csumW[(size_t)(ch * 128 + r + 1) * 512 + cc] = run;
  }
}

// ---------------------------------------------------------------------------
// K3: pre-shuffle dan_w1, ws_w0[0:512], ws_w0[512:640] into MFMA
// B-fragment-linear bf16:
//   shuf[((nt*KT+kt)*64+lane)*8 + j] = W[kt*32 + 8*(lane>>4)+j][nt*16+(lane&15)]
// ---------------------------------------------------------------------------
__global__ void k_prepack(const float* __restrict__ dan_w1, const float* __restrict__ ws_w0,
                          short* __restrict__ w1_shuf, short* __restrict__ w0s_shuf,
                          short* __restrict__ w0pe_shuf) {
  int o = blockIdx.x * 256 + threadIdx.x;  // 262144 + 65536 total
  if (o < 262144) {
    int j = o & 7, l = (o >> 3) & 63, kt = (o >> 9) & 15, nt = o >> 13;
    int k = kt * 32 + 8 * (l >> 4) + j;
    int n = nt * 16 + (l & 15);
    w1_shuf[o] = f2bf(dan_w1[(size_t)k * 512 + n]);
    w0s_shuf[o] = f2bf(ws_w0[(size_t)k * 512 + n]);
  } else {
    int o2 = o - 262144;  // [0, 65536)
    int j = o2 & 7, l = (o2 >> 3) & 63, kt = (o2 >> 9) & 3, nt = o2 >> 11;
    int k = 512 + kt * 32 + 8 * (l >> 4) + j;
    int n = nt * 16 + (l & 15);
    w0pe_shuf[o2] = f2bf(ws_w0[(size_t)k * 512 + n]);
  }
}

// ---------------------------------------------------------------------------
// K4: main fused kernel. 64 spans/block, 256 threads (4 waves, wave w owns
// output cols [128w,128w+128)). h -> LDS(bf16,XOR-swz) -> MFMA -> phrase ->
// same LDS -> MFMA (K=512) + in-register sinusoidal-feature MFMA (K=128)
// -> epilogue (relu + dot ws_w1). LDS = exactly 64 KiB -> 2 blocks/CU.
// ---------------------------------------------------------------------------
__launch_bounds__(256, 2)
__global__ void k_main(const int* __restrict__ spans_start, const int* __restrict__ spans_len,
                       const float* __restrict__ csumW, const short* __restrict__ w1_shuf,
                       const short* __restrict__ w0s_shuf, const short* __restrict__ w0pe_shuf,
                       const float* __restrict__ b0, const float* __restrict__ b1,
                       const float* __restrict__ bs0, const float* __restrict__ ws_w1,
                       const float* __restrict__ ws_b1, float* __restrict__ out) {
  __shared__ short tileS[BM * 512];  // 64 KiB: holds h, then phrase, then scores

  const int tid = threadIdx.x;
  const int lane = tid & 63;
  const int w = tid >> 6;        // wave 0..3
  const int g = lane >> 4;       // 16-lane group 0..3
  const int c = lane & 15;

  // XCD-bijective block swizzle (m204): consecutive swizzled ids stay on one XCD
  const int nwg = gridDim.x;
  const int q = nwg >> 3, r = nwg & 7;
  const int xcd = blockIdx.x & 7, sub = blockIdx.x >> 3;
  const int bid = (xcd < r ? xcd * (q + 1) : r * (q + 1) + (xcd - r) * q) + sub;
  const int cb = bid * BM;

  // ---- Phase 1: h[m][k] = relu((csumW[en]-csumW[st])*inv + b0[k]) -> tileS
  const float4 bb0 = *(const float4*)(b0 + 8 * lane);
  const float4 bb1 = *(const float4*)(b0 + 8 * lane + 4);
  for (int rep = 0; rep < 16; ++rep) {
    int m = 4 * rep + w;  // wave-uniform row
    int ch = cb + m;
    if (ch >= M_TOTAL) ch = M_TOTAL - 1;
    int st = spans_start[ch];
    int ln = spans_len[ch];
    int en = st + ln;
    float inv = 1.0f / (float)ln;
    const float* pe_ = csumW + (size_t)en * 512 + 8 * lane;
    const float* ps_ = csumW + (size_t)st * 512 + 8 * lane;
    float4 e0 = *(const float4*)pe_, e1 = *(const float4*)(pe_ + 4);
    float4 s0 = *(const float4*)ps_, s1 = *(const float4*)(ps_ + 4);
    float hv[8];
    hv[0] = (e0.x - s0.x) * inv + bb0.x;
    hv[1] = (e0.y - s0.y) * inv + bb0.y;
    hv[2] = (e0.z - s0.z) * inv + bb0.z;
    hv[3] = (e0.w - s0.w) * inv + bb0.w;
    hv[4] = (e1.x - s1.x) * inv + bb1.x;
    hv[5] = (e1.y - s1.y) * inv + bb1.y;
    hv[6] = (e1.z - s1.z) * inv + bb1.z;
    hv[7] = (e1.w - s1.w) * inv + bb1.w;
    short8 hs;
#pragma unroll
    for (int j = 0; j < 8; ++j) hs[j] = f2bf(fmaxf(hv[j], 0.f));
    int idx = m * 512 + (((16 * lane) ^ ((m & 7) << 4)) >> 1);
    *(short8*)(tileS + idx) = hs;
  }
  __syncthreads();

  const f32x4 zero4 = {0.f, 0.f, 0.f, 0.f};
  f32x4 acc[4][8];

  // GEMM over tileS (A, bf16, XOR-swizzled) x shuffled weights (B). K=512.
  auto do_gemm = [&](const short* __restrict__ Wsh) {
#pragma unroll
    for (int mt = 0; mt < 4; ++mt)
#pragma unroll
      for (int i = 0; i < 8; ++i) acc[mt][i] = zero4;
    const short8* W = (const short8*)Wsh;
#pragma unroll 2
    for (int kt = 0; kt < 16; ++kt) {
      short8 a[4];
#pragma unroll
      for (int mt = 0; mt < 4; ++mt) {
        int row = c + 16 * mt;
        int idx = row * 512 + (((kt * 64 + 16 * g) ^ ((c & 7) << 4)) >> 1);
        a[mt] = *(const short8*)(tileS + idx);
      }
#pragma unroll
      for (int i = 0; i < 8; ++i) {
        short8 bfrag = W[((8 * w + i) * 16 + kt) * 64 + lane];
#pragma unroll
        for (int mt = 0; mt < 4; ++mt)
          acc[mt][i] = __builtin_amdgcn_mfma_f32_16x16x32_bf16(a[mt], bfrag, acc[mt][i], 0, 0, 0);
      }
    }
  };

  // ---- Phase 2: phrase = relu(h @ w1 + b1)
  do_gemm(w1_shuf);
  __syncthreads();  // all reads of h complete before overwriting tileS
#pragma unroll
  for (int i = 0; i < 8; ++i) {
    int n = c + 16 * (8 * w + i);
    float bias = b1[n];
#pragma unroll
    for (int mt = 0; mt < 4; ++mt) {
#pragma unroll
      for (int r = 0; r < 4; ++r) {
        int m = 16 * mt + 4 * g + r;
        float v = acc[mt][i][r] + bias;
        v = v > 0.f ? v : 0.f;
        int idx = m * 512 + ((((2 * n) ^ ((m & 7) << 4))) >> 1);
        tileS[idx] = f2bf(v);
      }
    }
  }
  __syncthreads();

  // ---- Phase 3a: s_pre = phrase @ ws_w0[0:512]
  do_gemm(w0s_shuf);

  // ---- Phase 3b: s_pre += feats @ ws_w0[512:640]  (K=128, feats in-register)
  // A-frag: lane needs feats[row=c+16mt][k=kt*32+8g+j]; k decomposes as
  // tbl=kt (start,end,len,mid), idx8=8g+j: idx8<16 -> sin(d=idx8), else cos.
  // cos folded as sin(x+pi/2); per-lane d = 8*(g&1)+j, phase = (g>=2)*pi/2.
  {
    float x4v[4][4];
#pragma unroll
    for (int mt = 0; mt < 4; ++mt) {
      int ch = cb + c + 16 * mt;
      if (ch >= M_TOTAL) ch = M_TOTAL - 1;
      float st = (float)spans_start[ch];
      float ln = (float)spans_len[ch];
      x4v[mt][0] = st;
      x4v[mt][1] = st + ln;
      x4v[mt][2] = ln;
      x4v[mt][3] = st + 0.5f * ln;
    }
    float fr[8];
    float dbase = 8.0f * (float)(g & 1);
#pragma unroll
    for (int j = 0; j < 8; ++j)
      fr[j] = __expf(-0.5756462732485115f * (dbase + (float)j));  // ln(1e4)/16
    const float ph = (g >= 2) ? 1.5707963267948966f : 0.0f;
    const short8* Wpe = (const short8*)w0pe_shuf;
#pragma unroll
    for (int kt = 0; kt < 4; ++kt) {
      short8 af[4];
#pragma unroll
      for (int mt = 0; mt < 4; ++mt) {
#pragma unroll
        for (int j = 0; j < 8; ++j)
          af[mt][j] = f2bf(__sinf(x4v[mt][kt] * fr[j] + ph));
      }
#pragma unroll
      for (int i = 0; i < 8; ++i) {
        short8 bfrag = Wpe[((8 * w + i) * 4 + kt) * 64 + lane];
#pragma unroll
        for (int mt = 0; mt < 4; ++mt)
          acc[mt][i] = __builtin_amdgcn_mfma_f32_16x16x32_bf16(af[mt], bfrag, acc[mt][i], 0, 0, 0);
      }
    }
  }
  __syncthreads();  // phrase reads done; tileS reusable for score partials

  // ---- Phase 4: s = relu(s_pre + bs0); score = s . ws_w1
  float* scoreF = (float*)tileS;
  float bsv[8], w1v[8];
#pragma unroll
  for (int i = 0; i < 8; ++i) {
    int n = c + 16 * (8 * w + i);
    bsv[i] = bs0[n];
    w1v[i] = ws_w1[n];
  }
#pragma unroll
  for (int mt = 0; mt < 4; ++mt) {
#pragma unroll
    for (int r = 0; r < 4; ++r) {
      int m = 16 * mt + 4 * g + r;
      float p = 0.f;
#pragma unroll
      for (int i = 0; i < 8; ++i) {
        float v = acc[mt][i][r] + bsv[i];
        p += fmaxf(v, 0.f) * w1v[i];
      }
      p += __shfl_xor(p, 1);
      p += __shfl_xor(p, 2);
      p += __shfl_xor(p, 4);
      p += __shfl_xor(p, 8);
      if (c == 0) scoreF[w * 64 + m] = p;
    }
  }
  __syncthreads();
  if (tid < 64) {
    int ch = cb + tid;
    if (ch < M_TOTAL)
      out[ch] = scoreF[tid] + scoreF[64 + tid] + scoreF[128 + tid] + scoreF[192 + tid] + ws_b1[0];
  }
}

// ---------------------------------------------------------------------------
extern "C" void kernel_launch(void* const* d_in, const int* in_sizes, int n_in,
                              void* d_out, int out_size, void* d_ws, size_t ws_size,
                              hipStream_t stream) {
  const int* sentence = (const int*)d_in[0];
  const int* pos_tags = (const int*)d_in[1];
  const int* sp_start = (const int*)d_in[2];
  const int* sp_len   = (const int*)d_in[3];
  const float* We_wrd = (const float*)d_in[4];
  const float* We_pos = (const float*)d_in[5];
  const float* dan_w0 = (const float*)d_in[6];
  const float* dan_b0 = (const float*)d_in[7];
  const float* dan_w1 = (const float*)d_in[8];
  const float* dan_b1 = (const float*)d_in[9];
  const float* ws_w0  = (const float*)d_in[10];
  const float* ws_b0  = (const float*)d_in[11];
  const float* ws_w1  = (const float*)d_in[12];
  const float* ws_b1  = (const float*)d_in[13];
  float* out = (float*)d_out;

  char* ws = (char*)d_ws;
  float* embW     = (float*)(ws);              // 4,194,304 B
  float* csumW    = (float*)(ws + 4194304);    // 4,196,352 B
  float* cSum     = (float*)(ws + 8390656);    //    32,768 B
  float* cPre     = (float*)(ws + 8423424);    //    32,768 B
  short* w1_shuf  = (short*)(ws + 8456192);    //   524,288 B
  short* w0s_shuf = (short*)(ws + 8980480);    //   524,288 B
  short* w0pe_shuf= (short*)(ws + 9504768);    //   131,072 B -> total 9,635,840 B

  k_embW<<<128, 512, 0, stream>>>(sentence, pos_tags, We_wrd, We_pos, dan_w0, embW);
  k_scan_a<<<32, 256, 0, stream>>>(embW, cSum);
  k_scan_b<<<2, 256, 0, stream>>>(cSum, cPre);
  k_scan_c<<<32, 256, 0, stream>>>(embW, cPre, csumW);
  k_prepack<<<1280, 256, 0, stream>>>(dan_w1, ws_w0, w1_shuf, w0s_shuf, w0pe_shuf);
  k_main<<<638, 256, 0, stream>>>(sp_start, sp_len, csumW, w1_shuf, w0s_shuf, w0pe_shuf,
                                  dan_b0, dan_b1, ws_b0, ws_w1, ws_b1, out);
}

// Round 5
// 244.585 us; speedup vs baseline: 1.7056x; 1.1401x over previous
//
#include <hip/hip_runtime.h>

typedef __attribute__((ext_vector_type(8))) short short8;
typedef __attribute__((ext_vector_type(4))) float f32x4;

#define M_TOTAL 40770   // number of spans
#define NTOK    2048
#define HD      512
#define BM      64      // spans per block in main kernel

__device__ __forceinline__ short f2bf(float f) {
  unsigned u = __builtin_bit_cast(unsigned, f);
  u += 0x7FFFu + ((u >> 16) & 1u);
  return (short)(u >> 16);
}

// ---------------------------------------------------------------------------
// K1: embW[t] = concat(We_pos[tag], We_wrd[word]) @ dan_w0   [2048,512] fp32
// block: 8 tokens, 512 threads (thread owns one output column n)
// ---------------------------------------------------------------------------
__global__ void k_embW(const int* __restrict__ sentence, const int* __restrict__ pos_tags,
                       const float* __restrict__ We_wrd, const float* __restrict__ We_pos,
                       const float* __restrict__ dan_w0, float* __restrict__ embW) {
  __shared__ float rowf[8][512];   // 16 KB
  const int tid = threadIdx.x;
  const int b = blockIdx.x;
  for (int p = 0; p < 8; ++p) {
    int idx = p * 512 + tid;
    int m = idx >> 9, k = idx & 511;
    int tk = b * 8 + m;
    rowf[m][k] = (k < 256) ? We_pos[pos_tags[tk] * 256 + k]
                           : We_wrd[sentence[tk] * 256 + (k - 256)];
  }
  __syncthreads();
  float acc[8] = {0.f, 0.f, 0.f, 0.f, 0.f, 0.f, 0.f, 0.f};
  const int n = tid;
  for (int k4 = 0; k4 < 512; k4 += 4) {
    float w0 = dan_w0[(k4 + 0) * 512 + n];
    float w1 = dan_w0[(k4 + 1) * 512 + n];
    float w2 = dan_w0[(k4 + 2) * 512 + n];
    float w3 = dan_w0[(k4 + 3) * 512 + n];
#pragma unroll
    for (int m = 0; m < 8; ++m) {
      float4 rv = *(const float4*)&rowf[m][k4];
      acc[m] += rv.x * w0;
      acc[m] += rv.y * w1;
      acc[m] += rv.z * w2;
      acc[m] += rv.w * w3;
    }
  }
#pragma unroll
  for (int m = 0; m < 8; ++m)
    embW[(size_t)(b * 8 + m) * 512 + n] = acc[m];
}

// ---------------------------------------------------------------------------
// K2a/b/c: column-wise inclusive scan of embW (chunked 16 rows, 128 chunks)
// ---------------------------------------------------------------------------
__global__ void k_scan_a(const float* __restrict__ embW, float* __restrict__ cSum) {
  int b = blockIdx.x, t = threadIdx.x;
  int ch = b >> 1, cc = (b & 1) * 256 + t;
  float s = 0.f;
  for (int r = 0; r < 16; ++r) s += embW[(size_t)(ch * 16 + r) * 512 + cc];
  cSum[ch * 512 + cc] = s;
}
__global__ void k_scan_b(const float* __restrict__ cSum, float* __restrict__ cPre) {
  int cc = blockIdx.x * 256 + threadIdx.x;
  float run = 0.f;
  for (int ch = 0; ch < 128; ++ch) {
    cPre[ch * 512 + cc] = run;
    run += cSum[ch * 512 + cc];
  }
}
__global__ void k_scan_c(const float* __restrict__ embW, const float* __restrict__ cPre,
                         float* __restrict__ csumW) {
  int b = blockIdx.x, t = threadIdx.x;
  int ch = b >> 1, cc = (b & 1) * 256 + t;
  float run = cPre[ch * 512 + cc];
  if (ch == 0) csumW[cc] = 0.f;
  for (int r = 0; r < 16; ++r) {
    run += embW[(size_t)(ch * 16 + r) * 512 + cc];
    csumW[(size_t)(ch * 16 + r + 1) * 512 + cc] = run;
  }
}

// ---------------------------------------------------------------------------
// K3: pre-shuffle dan_w1, ws_w0[0:512], ws_w0[512:640] into MFMA
// B-fragment-linear bf16. Block b = one k-row (coalesced reads), thread = n.
//   o = ((n>>4)*KT + kt)*512 + g*128 + (n&15)*8 + j,  k = kt*32 + 8g + j
// ---------------------------------------------------------------------------
__global__ void k_prepack(const float* __restrict__ dan_w1, const float* __restrict__ ws_w0,
                          short* __restrict__ w1_shuf, short* __restrict__ w0s_shuf,
                          short* __restrict__ w0pe_shuf) {
  const int k = blockIdx.x;     // 0..639
  const int n = threadIdx.x;    // 0..511
  const int g = (k >> 3) & 3, j = k & 7;
  if (k < 512) {
    int o = ((n >> 4) * 16 + (k >> 5)) * 512 + g * 128 + (n & 15) * 8 + j;
    w1_shuf[o] = f2bf(dan_w1[(size_t)k * 512 + n]);
    w0s_shuf[o] = f2bf(ws_w0[(size_t)k * 512 + n]);
  } else {
    int o2 = ((n >> 4) * 4 + ((k >> 5) - 16)) * 512 + g * 128 + (n & 15) * 8 + j;
    w0pe_shuf[o2] = f2bf(ws_w0[(size_t)k * 512 + n]);
  }
}

// ---------------------------------------------------------------------------
// K4: main fused kernel. 64 spans/block, 512 threads (8 waves, wave w owns
// output cols [64w,64w+64)). acc[4][4] = 64 AGPR; launch_bounds(512,4) caps
// combined regs at 128/wave -> 4 waves/SIMD (2 blocks/CU, LDS 64 KiB).
// ---------------------------------------------------------------------------
__launch_bounds__(512, 4)
__global__ void k_main(const int* __restrict__ spans_start, const int* __restrict__ spans_len,
                       const float* __restrict__ csumW, const short* __restrict__ w1_shuf,
                       const short* __restrict__ w0s_shuf, const short* __restrict__ w0pe_shuf,
                       const float* __restrict__ b0, const float* __restrict__ b1,
                       const float* __restrict__ bs0, const float* __restrict__ ws_w1,
                       const float* __restrict__ ws_b1, float* __restrict__ out) {
  __shared__ short tileS[BM * 512];  // 64 KiB: holds h, then phrase, then scores

  const int tid = threadIdx.x;
  const int lane = tid & 63;
  const int w = tid >> 6;        // wave 0..7
  const int g = lane >> 4;       // 16-lane group 0..3
  const int c = lane & 15;

  // XCD-bijective block swizzle (m204)
  const int nwg = gridDim.x;
  const int q = nwg >> 3, r = nwg & 7;
  const int xcd = blockIdx.x & 7, sub = blockIdx.x >> 3;
  const int bid = (xcd < r ? xcd * (q + 1) : r * (q + 1) + (xcd - r) * q) + sub;
  const int cb = bid * BM;

  // ---- Phase 1: h[m][k] = relu((csumW[en]-csumW[st])*inv + b0[k]) -> tileS
  {
    const float4 bb0 = *(const float4*)(b0 + 8 * lane);
    const float4 bb1 = *(const float4*)(b0 + 8 * lane + 4);
    for (int rep = 0; rep < 8; ++rep) {
      int m = 8 * rep + w;  // wave-uniform row
      int ch = cb + m;
      if (ch >= M_TOTAL) ch = M_TOTAL - 1;
      int st = spans_start[ch];
      int ln = spans_len[ch];
      int en = st + ln;
      float inv = 1.0f / (float)ln;
      const float* pe_ = csumW + (size_t)en * 512 + 8 * lane;
      const float* ps_ = csumW + (size_t)st * 512 + 8 * lane;
      float4 e0 = *(const float4*)pe_, e1 = *(const float4*)(pe_ + 4);
      float4 s0 = *(const float4*)ps_, s1 = *(const float4*)(ps_ + 4);
      float hv[8];
      hv[0] = (e0.x - s0.x) * inv + bb0.x;
      hv[1] = (e0.y - s0.y) * inv + bb0.y;
      hv[2] = (e0.z - s0.z) * inv + bb0.z;
      hv[3] = (e0.w - s0.w) * inv + bb0.w;
      hv[4] = (e1.x - s1.x) * inv + bb1.x;
      hv[5] = (e1.y - s1.y) * inv + bb1.y;
      hv[6] = (e1.z - s1.z) * inv + bb1.z;
      hv[7] = (e1.w - s1.w) * inv + bb1.w;
      short8 hs;
#pragma unroll
      for (int j = 0; j < 8; ++j) hs[j] = f2bf(fmaxf(hv[j], 0.f));
      int idx = m * 512 + (((16 * lane) ^ ((m & 7) << 4)) >> 1);
      *(short8*)(tileS + idx) = hs;
    }
  }
  __syncthreads();

  const f32x4 zero4 = {0.f, 0.f, 0.f, 0.f};
  f32x4 acc[4][4];   // [mt][i] -> 64 AGPR

  // GEMM over tileS (A, bf16, XOR-swizzled) x shuffled weights (B). K=512.
  auto do_gemm = [&](const short* __restrict__ Wsh) {
#pragma unroll
    for (int mt = 0; mt < 4; ++mt)
#pragma unroll
      for (int i = 0; i < 4; ++i) acc[mt][i] = zero4;
    const short8* W = (const short8*)Wsh;
#pragma unroll 2
    for (int kt = 0; kt < 16; ++kt) {
      short8 a[4];
#pragma unroll
      for (int mt = 0; mt < 4; ++mt) {
        int row = c + 16 * mt;
        int idx = row * 512 + (((kt * 64 + 16 * g) ^ ((c & 7) << 4)) >> 1);
        a[mt] = *(const short8*)(tileS + idx);
      }
#pragma unroll
      for (int i = 0; i < 4; ++i) {
        short8 bfrag = W[((4 * w + i) * 16 + kt) * 64 + lane];
#pragma unroll
        for (int mt = 0; mt < 4; ++mt)
          acc[mt][i] = __builtin_amdgcn_mfma_f32_16x16x32_bf16(a[mt], bfrag, acc[mt][i], 0, 0, 0);
      }
    }
  };

  // ---- Phase 2: phrase = relu(h @ w1 + b1)
  do_gemm(w1_shuf);
  __syncthreads();  // all reads of h complete before overwriting tileS
#pragma unroll
  for (int i = 0; i < 4; ++i) {
    int n = c + 16 * (4 * w + i);
    float bias = b1[n];
#pragma unroll
    for (int mt = 0; mt < 4; ++mt) {
#pragma unroll
      for (int r = 0; r < 4; ++r) {
        int m = 16 * mt + 4 * g + r;
        float v = acc[mt][i][r] + bias;
        v = v > 0.f ? v : 0.f;
        int idx = m * 512 + ((((2 * n) ^ ((m & 7) << 4))) >> 1);
        tileS[idx] = f2bf(v);
      }
    }
  }
  __syncthreads();

  // ---- Phase 3a: s_pre = phrase @ ws_w0[0:512]
  do_gemm(w0s_shuf);

  // ---- Phase 3b: s_pre += feats @ ws_w0[512:640]  (K=128, feats in-register)
  // A-frag: lane needs feats[row=c+16mt][k=kt*32+8g+j]; tbl=kt (start,end,len,
  // mid); idx8=8g+j: <16 -> sin(d), else cos. cos = sin(x+pi/2);
  // per-lane d = 8*(g&1)+j, phase = (g>=2)*pi/2.
  {
    float x4v[4][4];
#pragma unroll
    for (int mt = 0; mt < 4; ++mt) {
      int ch = cb + c + 16 * mt;
      if (ch >= M_TOTAL) ch = M_TOTAL - 1;
      float st = (float)spans_start[ch];
      float ln = (float)spans_len[ch];
      x4v[mt][0] = st;
      x4v[mt][1] = st + ln;
      x4v[mt][2] = ln;
      x4v[mt][3] = st + 0.5f * ln;
    }
    float fr[8];
    float dbase = 8.0f * (float)(g & 1);
#pragma unroll
    for (int j = 0; j < 8; ++j)
      fr[j] = __expf(-0.5756462732485115f * (dbase + (float)j));  // ln(1e4)/16
    const float ph = (g >= 2) ? 1.5707963267948966f : 0.0f;
    const short8* Wpe = (const short8*)w0pe_shuf;
#pragma unroll
    for (int kt = 0; kt < 4; ++kt) {
      short8 af[4];
#pragma unroll
      for (int mt = 0; mt < 4; ++mt) {
#pragma unroll
        for (int j = 0; j < 8; ++j)
          af[mt][j] = f2bf(__sinf(x4v[mt][kt] * fr[j] + ph));
      }
#pragma unroll
      for (int i = 0; i < 4; ++i) {
        short8 bfrag = Wpe[((4 * w + i) * 4 + kt) * 64 + lane];
#pragma unroll
        for (int mt = 0; mt < 4; ++mt)
          acc[mt][i] = __builtin_amdgcn_mfma_f32_16x16x32_bf16(af[mt], bfrag, acc[mt][i], 0, 0, 0);
      }
    }
  }
  __syncthreads();  // phrase reads done; tileS reusable for score partials

  // ---- Phase 4: s = relu(s_pre + bs0); score = s . ws_w1
  float* scoreF = (float*)tileS;
  float bsv[4], w1v[4];
#pragma unroll
  for (int i = 0; i < 4; ++i) {
    int n = c + 16 * (4 * w + i);
    bsv[i] = bs0[n];
    w1v[i] = ws_w1[n];
  }
#pragma unroll
  for (int mt = 0; mt < 4; ++mt) {
#pragma unroll
    for (int r = 0; r < 4; ++r) {
      int m = 16 * mt + 4 * g + r;
      float p = 0.f;
#pragma unroll
      for (int i = 0; i < 4; ++i) {
        float v = acc[mt][i][r] + bsv[i];
        p += fmaxf(v, 0.f) * w1v[i];
      }
      p += __shfl_xor(p, 1);
      p += __shfl_xor(p, 2);
      p += __shfl_xor(p, 4);
      p += __shfl_xor(p, 8);
      if (c == 0) scoreF[w * 64 + m] = p;
    }
  }
  __syncthreads();
  if (tid < 64) {
    int ch = cb + tid;
    if (ch < M_TOTAL) {
      float s = ws_b1[0];
#pragma unroll
      for (int ww = 0; ww < 8; ++ww) s += scoreF[ww * 64 + tid];
      out[ch] = s;
    }
  }
}

// ---------------------------------------------------------------------------
extern "C" void kernel_launch(void* const* d_in, const int* in_sizes, int n_in,
                              void* d_out, int out_size, void* d_ws, size_t ws_size,
                              hipStream_t stream) {
  const int* sentence = (const int*)d_in[0];
  const int* pos_tags = (const int*)d_in[1];
  const int* sp_start = (const int*)d_in[2];
  const int* sp_len   = (const int*)d_in[3];
  const float* We_wrd = (const float*)d_in[4];
  const float* We_pos = (const float*)d_in[5];
  const float* dan_w0 = (const float*)d_in[6];
  const float* dan_b0 = (const float*)d_in[7];
  const float* dan_w1 = (const float*)d_in[8];
  const float* dan_b1 = (const float*)d_in[9];
  const float* ws_w0  = (const float*)d_in[10];
  const float* ws_b0  = (const float*)d_in[11];
  const float* ws_w1  = (const float*)d_in[12];
  const float* ws_b1  = (const float*)d_in[13];
  float* out = (float*)d_out;

  char* ws = (char*)d_ws;
  float* embW     = (float*)(ws);              // 4,194,304 B
  float* csumW    = (float*)(ws + 4194304);    // 4,196,352 B
  float* cSum     = (float*)(ws + 8390656);    //   262,144 B
  float* cPre     = (float*)(ws + 8652800);    //   262,144 B
  short* w1_shuf  = (short*)(ws + 8914944);    //   524,288 B
  short* w0s_shuf = (short*)(ws + 9439232);    //   524,288 B
  short* w0pe_shuf= (short*)(ws + 9963520);    //   131,072 B -> total 10,094,592 B

  k_embW<<<256, 512, 0, stream>>>(sentence, pos_tags, We_wrd, We_pos, dan_w0, embW);
  k_scan_a<<<256, 256, 0, stream>>>(embW, cSum);
  k_scan_b<<<2, 256, 0, stream>>>(cSum, cPre);
  k_scan_c<<<256, 256, 0, stream>>>(embW, cPre, csumW);
  k_prepack<<<640, 512, 0, stream>>>(dan_w1, ws_w0, w1_shuf, w0s_shuf, w0pe_shuf);
  k_main<<<638, 512, 0, stream>>>(sp_start, sp_len, csumW, w1_shuf, w0s_shuf, w0pe_shuf,
                                  dan_b0, dan_b1, ws_b0, ws_w1, ws_b1, out);
}